// Round 5
// baseline (123.279 us; speedup 1.0000x reference)
//
#include <hip/hip_runtime.h>
#include <math.h>

// Problem constants: B=32, T=1024, D_IN=64, H=128, NH=4, HD=32, R=3
#define TT 1024

// ---------------------------------------------------------------------------
// k_qr: per-batch prologue (32 blocks, 256 thr).
//   xs = last row of Adj*x; y = theta*xs + theta_b; q = Wq*y + ipb_q;
//   z(n) = Wk(n)^T q(n); r(n) = theta^T z(n) / sqrt(32)  -> ws
// ---------------------------------------------------------------------------
__global__ __launch_bounds__(256) void k_qr(
    const float* __restrict__ x, const float* __restrict__ theta_w,
    const float* __restrict__ theta_b, const float* __restrict__ ipw,
    const float* __restrict__ ipb, float* __restrict__ r_out) {
  const int b = blockIdx.x;
  const int tid = threadIdx.x;
  __shared__ float s_xs[64];
  __shared__ float s_y[128];
  __shared__ float s_q[128];
  __shared__ float s_z[4][128];
  const float* __restrict__ xb = x + (size_t)b * TT * 64;
  const int g = tid >> 4, l16 = tid & 15;

  if (tid < 64) {
    float acc = xb[(TT - 1) * 64 + tid]
              + 0.5f        * xb[(TT - 2) * 64 + tid]
              + (1.f / 3.f) * xb[(TT - 3) * 64 + tid]
              + 0.25f       * xb[(TT - 4) * 64 + tid];
    s_xs[tid] = acc * (12.f / 25.f);
  }
  __syncthreads();
  for (int pass = 0; pass < 8; ++pass) {  // y[e] = theta_w[e,:].xs + theta_b
    const int e = pass * 16 + g;
    const float4 wv = *(const float4*)(theta_w + e * 64 + l16 * 4);
    const float* xs4 = &s_xs[l16 * 4];
    float acc = wv.x * xs4[0] + wv.y * xs4[1] + wv.z * xs4[2] + wv.w * xs4[3];
    acc += __shfl_xor(acc, 1); acc += __shfl_xor(acc, 2);
    acc += __shfl_xor(acc, 4); acc += __shfl_xor(acc, 8);
    if (l16 == 0) s_y[e] = acc + theta_b[e];
  }
  __syncthreads();
  for (int pass = 0; pass < 8; ++pass) {  // q[e] = Wq[e,:].y + ipb[e]
    const int e = pass * 16 + g;
    const float* wr = ipw + e * 128 + l16 * 8;
    const float* yy = &s_y[l16 * 8];
    float acc = 0.f;
    #pragma unroll
    for (int u = 0; u < 8; ++u) acc += wr[u] * yy[u];
    acc += __shfl_xor(acc, 1); acc += __shfl_xor(acc, 2);
    acc += __shfl_xor(acc, 4); acc += __shfl_xor(acc, 8);
    if (l16 == 0) s_q[e] = acc + ipb[e];
  }
  __syncthreads();
  for (int rep = 0; rep < 2; ++rep) {  // z[n][cc], coalesced along cc
    const int idx = tid + rep * 256;
    const int n = idx >> 7, cc = idx & 127;
    const float* qn = &s_q[n * 32];
    float acc = 0.f;
    for (int e = 0; e < 32; ++e) acc += ipw[(128 + n * 32 + e) * 128 + cc] * qn[e];
    s_z[n][cc] = acc;
  }
  __syncthreads();
  {  // r[n][d], coalesced along d; fold 1/sqrt(32)
    const int n = tid >> 6, d = tid & 63;
    const float* zn = s_z[n];
    float acc = 0.f;
    for (int cc = 0; cc < 128; ++cc) acc += theta_w[cc * 64 + d] * zn[cc];
    r_out[(b * 4 + n) * 64 + d] = acc * 0.17677669529663687f;
  }
}

// ---------------------------------------------------------------------------
// k_main: grid 512 = (b<<4)|chunk, 256 threads. x kept in REGISTERS:
// each thread owns rows ri = it*16+g (it=0..4), cols [4*l16, 4*l16+4) of the
// 80-row halo window (base = 64c-6). 5 independent float4 HBM loads issued
// up front (single latency hit). t via 16-lane shuffle-dots -> LDS; softmax
// (no max-sub; scores O(0.01)) with per-chunk partial denom; p~ via 7-tap;
// u partials from the SAME registers; 16-way g-reduction through LDS.
// ---------------------------------------------------------------------------
__global__ __launch_bounds__(256) void k_main(
    const float* __restrict__ x, const float* __restrict__ r_in,
    float* __restrict__ u_p, float* __restrict__ d_p) {
  const int b = blockIdx.x >> 4;
  const int c = blockIdx.x & 15;
  const int tid = threadIdx.x;
  const int base = c * 64 - 6;
  const int g = tid >> 4, l16 = tid & 15;

  __shared__ __align__(16) float s_r[256];
  __shared__ float s_t[4][80];
  __shared__ float s_e[4][76];
  __shared__ float s_p[4][76];
  __shared__ float s_pt[4][64];
  __shared__ __align__(16) float s_up[16][256];

  const float* __restrict__ xb = x + (size_t)b * TT * 64;

  // ---- issue all x loads immediately (registers, no LDS) -----------------
  float4 xv[5];
  #pragma unroll
  for (int it = 0; it < 5; ++it) {
    const int j = base + it * 16 + g;
    xv[it] = make_float4(0.f, 0.f, 0.f, 0.f);
    if (j >= 0 && j < TT)
      xv[it] = ((const float4*)(xb + (size_t)j * 64))[l16];
  }
  s_r[tid] = r_in[b * 256 + tid];
  __syncthreads();

  // ---- t[n][ri] via shuffle-dots from registers --------------------------
  {
    const float4 r0 = ((const float4*)(s_r +   0))[l16];
    const float4 r1 = ((const float4*)(s_r +  64))[l16];
    const float4 r2 = ((const float4*)(s_r + 128))[l16];
    const float4 r3 = ((const float4*)(s_r + 192))[l16];
    #pragma unroll
    for (int it = 0; it < 5; ++it) {
      const float4 v = xv[it];
      float p0 = v.x * r0.x + v.y * r0.y + v.z * r0.z + v.w * r0.w;
      float p1 = v.x * r1.x + v.y * r1.y + v.z * r1.z + v.w * r1.w;
      float p2 = v.x * r2.x + v.y * r2.y + v.z * r2.z + v.w * r2.w;
      float p3 = v.x * r3.x + v.y * r3.y + v.z * r3.z + v.w * r3.w;
      #pragma unroll
      for (int m = 1; m <= 8; m <<= 1) {
        p0 += __shfl_xor(p0, m);
        p1 += __shfl_xor(p1, m);
        p2 += __shfl_xor(p2, m);
        p3 += __shfl_xor(p3, m);
      }
      if (l16 == 0) {
        const int ri = it * 16 + g;
        s_t[0][ri] = p0; s_t[1][ri] = p1; s_t[2][ri] = p2; s_t[3][ri] = p3;
      }
    }
  }
  __syncthreads();

  // ---- scores -> e, p (sl in [3,72]); partial denom; p~ ------------------
  const int n = tid >> 6, l = tid & 63;
  #pragma unroll
  for (int rnd = 0; rnd < 2; ++rnd) {
    const int sl = (rnd == 0) ? (l + 3) : (l + 67);
    if (rnd == 0 || l < 6) {
      const int s = base + sl;
      float e_val = 0.f, p_val = 0.f;
      if (s >= 0 && s < TT) {
        float acc = 0.f, wsum = 0.f;
        #pragma unroll
        for (int dj = -3; dj <= 3; ++dj) {
          const int j = s + dj;
          if (j >= 0 && j < TT) {
            const float w = 1.f / (1.f + (float)(dj < 0 ? -dj : dj));
            acc += w * s_t[n][sl + dj];
            wsum += w;
          }
        }
        e_val = expf(acc / wsum);   // scores O(0.01): no max-sub needed
        p_val = e_val / wsum;       // fold row-normalization of Adj row s
      }
      s_e[n][sl] = e_val;
      s_p[n][sl] = p_val;
    }
  }
  __syncthreads();
  {  // partial denom over own s (sl = 6+l)
    float ev = s_e[n][6 + l];
    #pragma unroll
    for (int m = 32; m >= 1; m >>= 1) ev += __shfl_xor(ev, m);
    if (l == 0) d_p[blockIdx.x * 4 + n] = ev;
  }
  {  // p~ for own j (jl = l)
    float acc = 0.f;
    #pragma unroll
    for (int dj = -3; dj <= 3; ++dj)
      acc += (1.f / (1.f + (float)(dj < 0 ? -dj : dj))) * s_p[n][6 + l + dj];
    s_pt[n][l] = acc;
  }
  __syncthreads();

  // ---- u partials from registers; reduce over g through LDS --------------
  {
    float4 un[4];
    #pragma unroll
    for (int nn = 0; nn < 4; ++nn) un[nn] = make_float4(0.f, 0.f, 0.f, 0.f);
    #pragma unroll
    for (int it = 0; it < 5; ++it) {
      const int ri = it * 16 + g;
      if (ri >= 6 && ri < 70) {
        const int jl = ri - 6;
        const float4 v = xv[it];
        #pragma unroll
        for (int nn = 0; nn < 4; ++nn) {
          const float pv = s_pt[nn][jl];
          un[nn].x += pv * v.x; un[nn].y += pv * v.y;
          un[nn].z += pv * v.z; un[nn].w += pv * v.w;
        }
      }
    }
    #pragma unroll
    for (int nn = 0; nn < 4; ++nn)
      ((float4*)&s_up[g][nn * 64])[l16] = un[nn];
  }
  __syncthreads();
  {  // output o-index = tid = n*64+d; sum 16 g-partials (2-way bank = free)
    float acc = 0.f;
    #pragma unroll
    for (int gg = 0; gg < 16; ++gg) acc += s_up[gg][tid];
    u_p[(size_t)blockIdx.x * 256 + tid] = acc;
  }
}

// ---------------------------------------------------------------------------
// k_tail: 32 blocks x 256 thr. Reduce partials, normalize, tail chain.
// All 128-dots are 16-lane-group coalesced shuffle-dots.
// ---------------------------------------------------------------------------
__global__ __launch_bounds__(256) void k_tail(
    const float* __restrict__ u_p, const float* __restrict__ d_p,
    const float* __restrict__ theta_w, const float* __restrict__ theta_b,
    const float* __restrict__ ipw, const float* __restrict__ ipb,
    const float* __restrict__ Wout, const float* __restrict__ outb,
    const float* __restrict__ ln_g, const float* __restrict__ ln_b,
    const float* __restrict__ w1, const float* __restrict__ b1,
    const float* __restrict__ w2, const float* __restrict__ b2,
    float* __restrict__ out) {
  const int b = blockIdx.x;
  const int tid = threadIdx.x;
  __shared__ float s_u[256];
  __shared__ float s_w[4][128];
  __shared__ float s_o[128], s_a[128], s_ln[128], s_hid[128], s_red[2];
  __shared__ float s_dn[4];

  if (tid < 64) {  // denom reduce: head n = tid>>4, chunk cc = tid&15
    const int n = tid >> 4, cc = tid & 15;
    float v = d_p[(b * 16 + cc) * 4 + n];
    v += __shfl_xor(v, 1); v += __shfl_xor(v, 2);
    v += __shfl_xor(v, 4); v += __shfl_xor(v, 8);
    if (cc == 0) s_dn[n] = v;
  }
  __syncthreads();
  {  // u reduce + normalize (coalesced across tid)
    const int n = tid >> 6;
    float acc = 0.f;
    for (int cc = 0; cc < 16; ++cc)
      acc += u_p[(size_t)(b * 16 + cc) * 256 + tid];
    s_u[tid] = acc / s_dn[n];
  }
  __syncthreads();

  const int g = tid >> 4, l16 = tid & 15;
  for (int pass = 0; pass < 32; ++pass) {  // w[n][cc] = theta[cc,:].u_n + tb
    const int o = pass * 16 + g;           // 0..511
    const int n = o >> 7, cc = o & 127;
    const float4 wv = *(const float4*)(theta_w + cc * 64 + l16 * 4);
    const float* un = &s_u[n * 64 + l16 * 4];
    float acc = wv.x * un[0] + wv.y * un[1] + wv.z * un[2] + wv.w * un[3];
    acc += __shfl_xor(acc, 1); acc += __shfl_xor(acc, 2);
    acc += __shfl_xor(acc, 4); acc += __shfl_xor(acc, 8);
    if (l16 == 0) s_w[n][cc] = acc + theta_b[cc];
  }
  __syncthreads();
  for (int pass = 0; pass < 8; ++pass) {  // o[e] = Wv[256+e,:].w(n(e)) + bv
    const int e = pass * 16 + g;
    const float* wr = ipw + (256 + e) * 128 + l16 * 8;
    const float* wn = &s_w[e >> 5][l16 * 8];
    float acc = 0.f;
    #pragma unroll
    for (int u = 0; u < 8; ++u) acc += wr[u] * wn[u];
    acc += __shfl_xor(acc, 1); acc += __shfl_xor(acc, 2);
    acc += __shfl_xor(acc, 4); acc += __shfl_xor(acc, 8);
    if (l16 == 0) s_o[e] = acc + ipb[256 + e];
  }
  __syncthreads();
  for (int pass = 0; pass < 8; ++pass) {  // a[e] = Wout[e,:].o + outb[e]
    const int e = pass * 16 + g;
    const float* wr = Wout + e * 128 + l16 * 8;
    const float* oo = &s_o[l16 * 8];
    float acc = 0.f;
    #pragma unroll
    for (int u = 0; u < 8; ++u) acc += wr[u] * oo[u];
    acc += __shfl_xor(acc, 1); acc += __shfl_xor(acc, 2);
    acc += __shfl_xor(acc, 4); acc += __shfl_xor(acc, 8);
    if (l16 == 0) s_a[e] = acc + outb[e];
  }
  __syncthreads();
  // LayerNorm over 128 (waves 0,1 carry values)
  const float a = (tid < 128) ? s_a[tid] : 0.f;
  float sum = a;
  #pragma unroll
  for (int m = 32; m >= 1; m >>= 1) sum += __shfl_xor(sum, m);
  if (tid == 0) s_red[0] = sum;
  if (tid == 64) s_red[1] = sum;
  __syncthreads();
  const float mu = (s_red[0] + s_red[1]) * (1.f / 128.f);
  __syncthreads();
  const float dv = (tid < 128) ? (a - mu) : 0.f;
  float sq = dv * dv;
  #pragma unroll
  for (int m = 32; m >= 1; m >>= 1) sq += __shfl_xor(sq, m);
  if (tid == 0) s_red[0] = sq;
  if (tid == 64) s_red[1] = sq;
  __syncthreads();
  const float var = (s_red[0] + s_red[1]) * (1.f / 128.f);
  if (tid < 128)
    s_ln[tid] = dv / sqrtf(var + 1e-5f) * ln_g[tid] + ln_b[tid];
  __syncthreads();
  for (int pass = 0; pass < 8; ++pass) {  // hid[e] = gelu(W1[e,:].ln + b1)
    const int e = pass * 16 + g;
    const float* wr = w1 + e * 128 + l16 * 8;
    const float* ll = &s_ln[l16 * 8];
    float acc = 0.f;
    #pragma unroll
    for (int u = 0; u < 8; ++u) acc += wr[u] * ll[u];
    acc += __shfl_xor(acc, 1); acc += __shfl_xor(acc, 2);
    acc += __shfl_xor(acc, 4); acc += __shfl_xor(acc, 8);
    if (l16 == 0) {
      float h = acc + b1[e];
      s_hid[e] = 0.5f * h * (1.f + erff(h * 0.70710678118654752f));
    }
  }
  __syncthreads();
  if (g < 2) {  // final 2 outputs
    const float* wr = w2 + g * 128 + l16 * 8;
    const float* hh = &s_hid[l16 * 8];
    float acc = 0.f;
    #pragma unroll
    for (int u = 0; u < 8; ++u) acc += wr[u] * hh[u];
    acc += __shfl_xor(acc, 1); acc += __shfl_xor(acc, 2);
    acc += __shfl_xor(acc, 4); acc += __shfl_xor(acc, 8);
    if (l16 == 0) out[b * 2 + g] = acc + b2[g];
  }
}

extern "C" void kernel_launch(void* const* d_in, const int* in_sizes, int n_in,
                              void* d_out, int out_size, void* d_ws, size_t ws_size,
                              hipStream_t stream) {
  const float* x       = (const float*)d_in[0];
  const float* theta_w = (const float*)d_in[1];
  const float* theta_b = (const float*)d_in[2];
  const float* ipw     = (const float*)d_in[3];
  const float* ipb     = (const float*)d_in[4];
  const float* outw    = (const float*)d_in[5];
  const float* outb    = (const float*)d_in[6];
  const float* ln_g    = (const float*)d_in[7];
  const float* ln_b    = (const float*)d_in[8];
  const float* w1      = (const float*)d_in[9];
  const float* b1      = (const float*)d_in[10];
  const float* w2      = (const float*)d_in[11];
  const float* b2      = (const float*)d_in[12];

  float* ws  = (float*)d_ws;
  float* r   = ws;                     // 32*4*64  = 8192 floats
  float* u_p = ws + 8192;              // 512*256  = 131072 floats
  float* d_p = ws + 8192 + 131072;     // 512*4    = 2048 floats

  k_qr  <<< 32, 256, 0, stream>>>(x, theta_w, theta_b, ipw, ipb, r);
  k_main<<<512, 256, 0, stream>>>(x, r, u_p, d_p);
  k_tail<<< 32, 256, 0, stream>>>(u_p, d_p, theta_w, theta_b, ipw, ipb,
                                  outw, outb, ln_g, ln_b, w1, b1, w2, b2,
                                  (float*)d_out);
}